// Round 1
// 271.825 us; speedup vs baseline: 1.0260x; 1.0260x over previous
//
#include <hip/hip_runtime.h>

typedef unsigned short u16;
typedef u16 u16x4 __attribute__((ext_vector_type(4)));
typedef float f32x4 __attribute__((ext_vector_type(4)));
typedef __bf16 bf16x8 __attribute__((ext_vector_type(8)));
typedef __bf16 bf16x4 __attribute__((ext_vector_type(4)));

#define M_DIM 8192   // B*H = 4*2048
#define N_DIM 1024   // O
#define K_DIM 4096   // I*(D+1) = 1024*4

__device__ __forceinline__ u16 f2bf(float f) {
  unsigned u = __float_as_uint(f);
  u += 0x7FFFu + ((u >> 16) & 1u);   // round-to-nearest-even
  return (u16)(u >> 16);
}

// ---- kernel 1: W2[o][i*4+d] = ws[o][i] * w[o][d], bf16 [N][K] ----
__global__ __launch_bounds__(256) void k_w2(const float* __restrict__ w,
                                            const float* __restrict__ ws,
                                            u16* __restrict__ w2) {
  int idx = blockIdx.x * 256 + threadIdx.x;  // idx = o*1024 + i
  int o = idx >> 10;
  float s = ws[idx];
  f32x4 wv = *(const f32x4*)(w + o * 4);
  u16x4 r;
  r[0] = f2bf(s * wv[0]); r[1] = f2bf(s * wv[1]);
  r[2] = f2bf(s * wv[2]); r[3] = f2bf(s * wv[3]);
  *(u16x4*)(w2 + (size_t)idx * 4) = r;
}

// ---- kernel 2: fused cvt+GEMM. A = x fp32 [M][K] read directly;
// converted to bf16 in registers while staging into swizzled LDS.
// 128x128 tile, BK=64, 512 threads (8 waves). B (bf16 W2) staged via
// global_load_lds as before. A-loads for tile k+1 issued during compute
// of tile k (reg prefetch) so HBM latency hides under MFMA. ----
typedef __attribute__((address_space(1))) const void gvoid_t;
typedef __attribute__((address_space(3))) void lvoid_t;
__device__ __forceinline__ void gll16(const void* g, void* l) {
  __builtin_amdgcn_global_load_lds((gvoid_t*)g, (lvoid_t*)l, 16, 0, 0);
}

__device__ __forceinline__ void cvt_store(u16* dst, f32x4 a) {
  bf16x4 b;
  b[0] = (__bf16)a[0]; b[1] = (__bf16)a[1];
  b[2] = (__bf16)a[2]; b[3] = (__bf16)a[3];
  *(bf16x4*)dst = b;   // ds_write_b64
}

__global__ __launch_bounds__(512) void k_gemm(const float* __restrict__ A,
                                              const u16* __restrict__ Bt,
                                              float* __restrict__ C) {
  __shared__ u16 sA[128 * 64];  // 16 KB bf16 (swizzled)
  __shared__ u16 sB[128 * 64];  // 16 KB bf16 (swizzled)

  const int t    = threadIdx.x;
  const int lane = t & 63;
  const int wid  = t >> 6;           // 0..7

  // XCD-locality swizzle: 512 blocks, xcd ~ L&7. Give XCD x the 8
  // m-panels x*8..x*8+7 (each m-panel's 8 n-blocks co-resident on one
  // L2, so the 2 MB fp32 A panel is fetched into exactly one L2).
  const int L  = blockIdx.x;
  const int xc = L & 7;
  const int jj = L >> 3;             // 0..63
  const int m0 = (xc * 8 + (jj >> 3)) * 128;
  const int n0 = (jj & 7) * 128;

  // --- A staging geometry (fp32 -> bf16 in regs) ---
  // thread t handles rows (t>>4)+32j (j=0..3), fp32-quad q=t&15 of each.
  // LDS slot: 16B chunk c=q>>1 stored at c^(row&7); (32j)&7==0 so the
  // swizzled chunk index is the same for all 4 rows.
  const int ar  = t >> 4;            // base row 0..31
  const int aq  = t & 15;            // fp32 quad within 64-col k-step
  const int apc = (aq >> 1) ^ (ar & 7);
  const float* pA = A + (size_t)(m0 + ar) * K_DIM + aq * 4;
  u16* lA = sA + ar * 64 + apc * 8 + (aq & 1) * 4;

  // --- B staging via global_load_lds (unchanged, swizzled) ---
  const int s0 = t, s1 = t + 512;
  const int r0 = s0 >> 3, c0 = (s0 & 7) ^ (r0 & 7);
  const int r1 = s1 >> 3, c1 = (s1 & 7) ^ (r1 & 7);
  const u16* gB0 = Bt + (size_t)(n0 + r0) * K_DIM + c0 * 8;
  const u16* gB1 = Bt + (size_t)(n0 + r1) * K_DIM + c1 * 8;
  u16* lB0 = sB + s0 * 8;  u16* lB1 = sB + s1 * 8;

  // wave tile: 4(M)x2(N) waves of 32x64, each 2x4 MFMA 16x16x32 per k-step
  const int wm = (wid >> 1) * 32;
  const int wn = (wid & 1) * 64;
  const int fr = lane & 15;         // fragment row
  const int lc = lane >> 4;         // logical chunk within 32-wide k-step

  f32x4 acc[2][4];
#pragma unroll
  for (int i = 0; i < 2; i++)
#pragma unroll
    for (int j = 0; j < 4; j++) acc[i][j] = (f32x4){0.f, 0.f, 0.f, 0.f};

  // prologue: prefetch A quads for k0=0
  f32x4 pf0 = *(const f32x4*)(pA);
  f32x4 pf1 = *(const f32x4*)(pA + (size_t)32 * K_DIM);
  f32x4 pf2 = *(const f32x4*)(pA + (size_t)64 * K_DIM);
  f32x4 pf3 = *(const f32x4*)(pA + (size_t)96 * K_DIM);

  for (int k0 = 0; k0 < K_DIM; k0 += 64) {
    // LDS is free here (post 2nd barrier of previous iteration)
    cvt_store(lA,           pf0);
    cvt_store(lA + 32 * 64, pf1);
    cvt_store(lA + 64 * 64, pf2);
    cvt_store(lA + 96 * 64, pf3);
    gll16(gB0, lB0); gll16(gB1, lB1);
    gB0 += 64; gB1 += 64;
    __syncthreads();  // tiles ready (drains lgkm + vm)

    // issue next tile's A loads now; latency hides under the MFMAs,
    // drained by the barrier at loop bottom.
    if (k0 + 64 < K_DIM) {
      pA += 64;
      pf0 = *(const f32x4*)(pA);
      pf1 = *(const f32x4*)(pA + (size_t)32 * K_DIM);
      pf2 = *(const f32x4*)(pA + (size_t)64 * K_DIM);
      pf3 = *(const f32x4*)(pA + (size_t)96 * K_DIM);
    }

#pragma unroll
    for (int ks = 0; ks < 2; ks++) {
      bf16x8 af[2], bfr[4];
#pragma unroll
      for (int mi = 0; mi < 2; mi++) {
        int r  = wm + mi * 16 + fr;
        int pc = (ks * 4 + lc) ^ (r & 7);
        af[mi] = *(const bf16x8*)(sA + r * 64 + pc * 8);
      }
#pragma unroll
      for (int ni = 0; ni < 4; ni++) {
        int r  = wn + ni * 16 + fr;
        int pc = (ks * 4 + lc) ^ (r & 7);
        bfr[ni] = *(const bf16x8*)(sB + r * 64 + pc * 8);
      }
#pragma unroll
      for (int mi = 0; mi < 2; mi++)
#pragma unroll
        for (int ni = 0; ni < 4; ni++)
          acc[mi][ni] = __builtin_amdgcn_mfma_f32_16x16x32_bf16(
              af[mi], bfr[ni], acc[mi][ni], 0, 0, 0);
    }
    __syncthreads();  // protect LDS from next iteration's staging
  }

  // C/D layout: col = lane&15, row = (lane>>4)*4 + reg
  const int cr = (lane >> 4) * 4;
  const int cc = lane & 15;
#pragma unroll
  for (int mi = 0; mi < 2; mi++)
#pragma unroll
    for (int ni = 0; ni < 4; ni++) {
      float* cp = C + (size_t)(m0 + wm + mi * 16 + cr) * N_DIM +
                  (n0 + wn + ni * 16 + cc);
#pragma unroll
      for (int r = 0; r < 4; r++) cp[(size_t)r * N_DIM] = acc[mi][ni][r];
    }
}

extern "C" void kernel_launch(void* const* d_in, const int* in_sizes, int n_in,
                              void* d_out, int out_size, void* d_ws, size_t ws_size,
                              hipStream_t stream) {
  const float* x  = (const float*)d_in[0];   // (4,2048,1024,4) fp32
  const float* w  = (const float*)d_in[1];   // (1024,4) fp32
  const float* ws = (const float*)d_in[2];   // (1024,1024) fp32
  float* out = (float*)d_out;                // (4,2048,1024) fp32 = C[M][N]

  u16* w2 = (u16*)d_ws;                      // 4.2M u16 = 8 MB

  k_w2<<<4096, 256, 0, stream>>>(w, ws, w2);
  k_gemm<<<512, 512, 0, stream>>>(x, w2, out);
}